// Round 1
// 185.562 us; speedup vs baseline: 1.0081x; 1.0081x over previous
//
#include <hip/hip_runtime.h>
#include <hip/hip_bf16.h>
#include <stdint.h>

typedef __attribute__((ext_vector_type(8))) short short8;
typedef __attribute__((ext_vector_type(4))) float float4v;
typedef __attribute__((ext_vector_type(4))) unsigned short ushort4v;

#define Bq 2
#define Sq 2048
#define Dq 1024
#define Hq 16
#define HDq 64

// 0.125 * log2(e): folded into Q at the QKV-GEMM epilogue so attention can use
// exp2 directly with no per-score scaling.
#define QSCALE 0.18033688011112042f

__device__ __forceinline__ unsigned short f2bf(float f) {
  union { float f; uint32_t u; } v; v.f = f;
  uint32_t r = (v.u + 0x7FFFu + ((v.u >> 16) & 1u)) >> 16;
  return (unsigned short)r;
}

// packed f32x2 -> bf16x2 (v_cvt_pk_bf16_f32 on gfx950)
__device__ __forceinline__ uint32_t pk2bf(float a, float b) {
  union { __hip_bfloat162 h; uint32_t u; } cv;
  cv.h = __float22bfloat162_rn(make_float2(a, b));
  return cv.u;
}

// async global->LDS, 16B per lane; LDS dest is wave-uniform base + lane*16.
__device__ __forceinline__ void gl_lds16(const unsigned short* g, unsigned short* l) {
  __builtin_amdgcn_global_load_lds(
      (const __attribute__((address_space(1))) void*)g,
      (__attribute__((address_space(3))) void*)l, 16, 0, 0);
}

// One launch: x (blocks 0..4095) + 4 weights (blocks 4096..8191, contiguous dst).
__global__ __launch_bounds__(256) void cvt_all_kernel(
    const float* __restrict__ x,
    const float* __restrict__ w0, const float* __restrict__ w1,
    const float* __restrict__ w2, const float* __restrict__ w3,
    unsigned short* __restrict__ xb, unsigned short* __restrict__ wb) {
  const int bid = blockIdx.x;
  const float* src;
  unsigned short* dst;
  int idx;
  if (bid < 4096) {
    src = x; dst = xb;
    idx = bid * 256 + threadIdx.x;
  } else {
    int j = (bid - 4096) * 256 + threadIdx.x;  // float4 index across 4 weights
    int z = j >> 18;                           // 262144 float4 per weight
    src = (z == 0) ? w0 : (z == 1) ? w1 : (z == 2) ? w2 : w3;
    dst = wb + (size_t)z * 1048576;            // 1M shorts per weight
    idx = j & 262143;
  }
  float4v f = ((const float4v*)src)[idx];
  ushort4v o;
#pragma unroll
  for (int q = 0; q < 4; q++) o[q] = f2bf(f[q]);
  ((ushort4v*)dst)[idx] = o;
}

// C = A(bf16 MxK) @ W^T. MT x 128 tile, BK=64, global_load_lds staging.
// LDS layout XOR-swizzled on 16B granules (phys_g = g ^ (row&7)): at 128B row
// stride unswizzled b128 frag reads are 16-way bank conflicts; swizzled 2-way
// (free). Staging side absorbs the swizzle in the precomputed global address.
// QKV epilogue scales Q (z==0) by QSCALE in fp32 before bf16 rounding.
template <bool OUTPROJ, int MT>
__global__ __launch_bounds__(256) void gemm_bt_kernel(
    const unsigned short* __restrict__ A,
    const unsigned short* __restrict__ W0,
    const unsigned short* __restrict__ W1,
    const unsigned short* __restrict__ W2,
    unsigned short* __restrict__ q_dst,
    unsigned short* __restrict__ k_dst,
    unsigned short* __restrict__ v_dst,
    float* __restrict__ f_dst,
    const float* __restrict__ bias) {
  constexpr int K = 1024;
  constexpr int NMB = MT / 32;    // 16-row m-blocks per wave
  constexpr int APASS = MT / 32;  // staging passes for A (32 rows each)
  const int z = blockIdx.z;
  const unsigned short* W = (z == 0) ? W0 : (z == 1) ? W1 : W2;
  unsigned short* qkv = (z == 0) ? q_dst : (z == 1) ? k_dst : v_dst;

  __shared__ unsigned short Asm[MT * 64];
  __shared__ unsigned short Bsm[128 * 64];

  const int t = threadIdx.x;
  const int wave = t >> 6, lane = t & 63;
  const int quad = lane >> 4, l16 = lane & 15;
  const int wy = wave >> 1, wx = wave & 1;
  const int row0 = blockIdx.x * MT;
  const int col0 = blockIdx.y * 128;

  float4v zero = {0.f, 0.f, 0.f, 0.f};
  float4v acc[NMB][4];
#pragma unroll
  for (int i = 0; i < NMB; i++)
#pragma unroll
    for (int j = 0; j < 4; j++) acc[i][j] = zero;

  // staging geometry: pass i covers rows i*32..i*32+31; thread t -> row i*32+(t>>3),
  // phys granule t&7, logical granule (t&7)^((t>>3)&7). LDS slot = i*2048 + t*8.
  const int srow = t >> 3;
  const int sgl = ((t & 7) ^ (srow & 7)) << 3;  // logical col in shorts
  const unsigned short* gA[APASS];
  const unsigned short* gB[4];
#pragma unroll
  for (int i = 0; i < APASS; i++)
    gA[i] = A + (size_t)(row0 + i * 32 + srow) * K + sgl;
#pragma unroll
  for (int i = 0; i < 4; i++)
    gB[i] = W + (size_t)(col0 + i * 32 + srow) * K + sgl;

  const int swl = (l16 & 7);  // frag-read swizzle key

  for (int k0 = 0; k0 < K; k0 += 64) {
#pragma unroll
    for (int i = 0; i < APASS; i++) gl_lds16(gA[i] + k0, &Asm[i * 2048 + t * 8]);
#pragma unroll
    for (int i = 0; i < 4; i++) gl_lds16(gB[i] + k0, &Bsm[i * 2048 + t * 8]);
    __syncthreads();
    short8 af[NMB][2], bf[4][2];
#pragma unroll
    for (int ks = 0; ks < 2; ks++) {
#pragma unroll
      for (int mb = 0; mb < NMB; mb++) {
        int row = wy * (MT / 2) + mb * 16 + l16;
        int pg = (ks * 4 + quad) ^ swl;
        af[mb][ks] = *(const short8*)(&Asm[row * 64 + pg * 8]);
      }
#pragma unroll
      for (int nb = 0; nb < 4; nb++) {
        int row = wx * 64 + nb * 16 + l16;
        int pg = (ks * 4 + quad) ^ swl;
        bf[nb][ks] = *(const short8*)(&Bsm[row * 64 + pg * 8]);
      }
    }
#pragma unroll
    for (int ks = 0; ks < 2; ks++)
#pragma unroll
      for (int mb = 0; mb < NMB; mb++)
#pragma unroll
        for (int nb = 0; nb < 4; nb++)
          acc[mb][nb] = __builtin_amdgcn_mfma_f32_16x16x32_bf16(af[mb][ks], bf[nb][ks], acc[mb][nb], 0, 0, 0);
    __syncthreads();
  }

  const float qsc = (!OUTPROJ && z == 0) ? QSCALE : 1.0f;
#pragma unroll
  for (int mb = 0; mb < NMB; mb++) {
#pragma unroll
    for (int nb = 0; nb < 4; nb++) {
#pragma unroll
      for (int r = 0; r < 4; r++) {
        int row = row0 + wy * (MT / 2) + mb * 16 + quad * 4 + r;  // token index
        int o = col0 + wx * 64 + nb * 16 + l16;                   // output feature
        float val = acc[mb][nb][r];
        if (OUTPROJ) {
          f_dst[(size_t)row * 1024 + o] = val + bias[o];
        } else {
          int b = row >> 11, s = row & 2047;
          int h = o >> 6, hd = o & 63;
          qkv[(size_t)((b * Hq + h) * Sq + s) * HDq + hd] = f2bf(val * qsc);
        }
      }
    }
  }
}

// Flash attention: S^T trick (P in registers), 128-key tiles, sigma-permuted V
// (PV B-frags are single b128), global->reg prefetch, exp2 (scale pre-folded
// into Q), denominators via ones-column MFMA (C-layout aligned with of -> no
// shuffle reduce).
// v2: 8 waves x 16q = 128 q/block (512 threads). Same grid (16x32 = 512 blocks
// = 2 blocks/CU) and same K/V HBM traffic as the 4-wave version, but 16
// waves/CU = 4 waves/SIMD (was 2): doubles the wave pool available to overlap
// MFMA / exp2(trans) / LDS latency. Per-wave state halves (rb dim removed).
__global__ __launch_bounds__(512) void attn_kernel(
    const unsigned short* __restrict__ Q,
    const unsigned short* __restrict__ Kg,
    const unsigned short* __restrict__ Vg,
    unsigned short* __restrict__ ctx) {
  constexpr int KSTR = 68;   // Ksm stride (shorts)
  constexpr int VSTR = 136;  // Vsm stride (shorts)
  const int bh = blockIdx.y;
  const int q0 = blockIdx.x * 128;
  const int t = threadIdx.x;
  const int wave = t >> 6, lane = t & 63;
  const int quad = lane >> 4, l16 = lane & 15;

  __shared__ unsigned short Ksm[128 * KSTR];  // [key][hd]
  __shared__ unsigned short Vsm[64 * VSTR];   // [hd][sigma(key)]

  const unsigned short* Qb = Q + (size_t)bh * Sq * HDq;
  const unsigned short* Kb = Kg + (size_t)bh * Sq * HDq;
  const unsigned short* Vb = Vg + (size_t)bh * Sq * HDq;

  short8 qf[2];  // [ks]; wave owns 16 q-rows
#pragma unroll
  for (int ks = 0; ks < 2; ks++)
    qf[ks] = *(const short8*)(Qb + (size_t)(q0 + wave * 16 + l16) * HDq + ks * 32 + quad * 8);

  short8 ones;
#pragma unroll
  for (int j = 0; j < 8; j++) ones[j] = (short)0x3F80;  // bf16 1.0

  float4v zero = {0.f, 0.f, 0.f, 0.f};
  float4v of[4];
  float4v dsum = zero;
#pragma unroll
  for (int hb = 0; hb < 4; hb++) of[hb] = zero;

  // staging geometry for 512 threads:
  // K: thread t covers rows (t>>3) + i*64 (i=0,1), 8-short chunk (t&7)*8.
  // V: thread t covers keys vr2, vr2+1 at hd slice vc8..vc8+7 (wave-indexed).
  const int kr0 = t >> 3, kc = (t & 7) << 3;
  const int vr2 = (t & 63) * 2;
  const int vc8 = (t >> 6) << 3;
  const int sig = (vr2 & ~31) + (((vr2 >> 2) & 3) << 3) + (((vr2 >> 4) & 1) << 2) + (vr2 & 3);

  short8 kpr[2], vpr0, vpr1;
#pragma unroll
  for (int i = 0; i < 2; i++)
    kpr[i] = *(const short8*)(Kb + (size_t)(kr0 + i * 64) * HDq + kc);
  vpr0 = *(const short8*)(Vb + (size_t)vr2 * HDq + vc8);
  vpr1 = *(const short8*)(Vb + (size_t)(vr2 + 1) * HDq + vc8);

  for (int kt = 0; kt < Sq; kt += 128) {
#pragma unroll
    for (int i = 0; i < 2; i++)
      *(short8*)(&Ksm[(kr0 + i * 64) * KSTR + kc]) = kpr[i];
#pragma unroll
    for (int j = 0; j < 8; j++) {
      uint32_t pk = (uint32_t)(unsigned short)vpr0[j] |
                    ((uint32_t)(unsigned short)vpr1[j] << 16);
      *(uint32_t*)(&Vsm[(vc8 + j) * VSTR + sig]) = pk;
    }
    __syncthreads();

    if (kt + 128 < Sq) {
      const unsigned short* Kn = Kb + (size_t)(kt + 128) * HDq;
      const unsigned short* Vn = Vb + (size_t)(kt + 128) * HDq;
#pragma unroll
      for (int i = 0; i < 2; i++)
        kpr[i] = *(const short8*)(Kn + (size_t)(kr0 + i * 64) * HDq + kc);
      vpr0 = *(const short8*)(Vn + (size_t)vr2 * HDq + vc8);
      vpr1 = *(const short8*)(Vn + (size_t)(vr2 + 1) * HDq + vc8);
    }

#pragma unroll
    for (int p = 0; p < 4; p++) {
      float4v sf[2] = {zero, zero};
#pragma unroll
      for (int s = 0; s < 2; s++)
#pragma unroll
        for (int ks = 0; ks < 2; ks++) {
          short8 kf = *(const short8*)(&Ksm[(p * 32 + s * 16 + l16) * KSTR + ks * 32 + quad * 8]);
          sf[s] = __builtin_amdgcn_mfma_f32_16x16x32_bf16(kf, qf[ks], sf[s], 0, 0, 0);
        }
      union { uint32_t u[4]; short8 v; } pw;
#pragma unroll
      for (int s = 0; s < 2; s++)
#pragma unroll
        for (int rp = 0; rp < 2; rp++) {
          float pa = __builtin_amdgcn_exp2f(sf[s][rp * 2]);
          float pb = __builtin_amdgcn_exp2f(sf[s][rp * 2 + 1]);
          pw.u[s * 2 + rp] = pk2bf(pa, pb);
        }
      short8 pf = pw.v;
      dsum = __builtin_amdgcn_mfma_f32_16x16x32_bf16(pf, ones, dsum, 0, 0, 0);
#pragma unroll
      for (int hb = 0; hb < 4; hb++) {
        short8 vf = *(const short8*)(&Vsm[(hb * 16 + l16) * VSTR + p * 32 + quad * 8]);
        of[hb] = __builtin_amdgcn_mfma_f32_16x16x32_bf16(pf, vf, of[hb], 0, 0, 0);
      }
    }
    __syncthreads();
  }

  const int b = bh >> 4, h = bh & 15;
  float4v dinv;
#pragma unroll
  for (int r = 0; r < 4; r++) dinv[r] = 1.0f / dsum[r];
#pragma unroll
  for (int hb = 0; hb < 4; hb++)
#pragma unroll
    for (int r = 0; r < 4; r++) {
      int srow = q0 + wave * 16 + quad * 4 + r;
      int d = h * 64 + hb * 16 + l16;
      ctx[(size_t)(b * Sq + srow) * Dq + d] = f2bf(of[hb][r] * dinv[r]);
    }
}

extern "C" void kernel_launch(void* const* d_in, const int* in_sizes, int n_in,
                              void* d_out, int out_size, void* d_ws, size_t ws_size,
                              hipStream_t stream) {
  (void)in_sizes; (void)n_in; (void)out_size; (void)ws_size;
  const float* x  = (const float*)d_in[0];
  const float* wq = (const float*)d_in[1];
  const float* wk = (const float*)d_in[2];
  const float* wv = (const float*)d_in[3];
  const float* wo = (const float*)d_in[4];
  const float* bo = (const float*)d_in[5];
  float* out = (float*)d_out;

  char* ws = (char*)d_ws;
  const size_t MB = 1u << 20;
  unsigned short* xb  = (unsigned short*)(ws + 0 * MB);   // 8 MB  (4096x1024 bf16)
  unsigned short* wqb = (unsigned short*)(ws + 8 * MB);   // 2 MB each, contiguous
  unsigned short* wkb = (unsigned short*)(ws + 10 * MB);
  unsigned short* wvb = (unsigned short*)(ws + 12 * MB);
  unsigned short* wob = (unsigned short*)(ws + 14 * MB);
  unsigned short* qb  = (unsigned short*)(ws + 16 * MB);  // 8 MB  (B,H,S,HD), pre-scaled
  unsigned short* kb  = (unsigned short*)(ws + 24 * MB);  // 8 MB
  unsigned short* vb  = (unsigned short*)(ws + 32 * MB);  // 8 MB
  unsigned short* cxb = (unsigned short*)(ws + 40 * MB);  // 8 MB  (B,S,D)

  cvt_all_kernel<<<8192, 256, 0, stream>>>(x, wq, wk, wv, wo, xb, wqb);

  gemm_bt_kernel<false, 128><<<dim3(32, 8, 3), 256, 0, stream>>>(
      xb, wqb, wkb, wvb, qb, kb, vb, nullptr, nullptr);
  attn_kernel<<<dim3(16, 32), 512, 0, stream>>>(qb, kb, vb, cxb);
  gemm_bt_kernel<true, 64><<<dim3(64, 8, 1), 256, 0, stream>>>(
      cxb, wob, wob, wob, nullptr, nullptr, nullptr, out, bo);
}